// Round 6
// baseline (537.996 us; speedup 1.0000x reference)
//
#include <hip/hip_runtime.h>
#include <stdint.h>
#include <stddef.h>

typedef unsigned short u16;
typedef __attribute__((ext_vector_type(8))) short short8;
typedef __attribute__((ext_vector_type(4))) float f32x4;

#define DEVI __device__ __forceinline__

DEVI u16 f2bf(float f) {
  union { float f; unsigned u; } c; c.f = f;
  unsigned r = c.u + 0x7fff + ((c.u >> 16) & 1);
  return (u16)(r >> 16);
}

DEVI short8 pack8(f32x4 a, f32x4 b) {
  short8 v;
#pragma unroll
  for (int i = 0; i < 4; i++) { v[i] = (short)f2bf(a[i]); v[i + 4] = (short)f2bf(b[i]); }
  return v;
}

typedef __attribute__((address_space(1))) const void global_cvoid;
typedef __attribute__((address_space(3))) void lds_void;

// ---------------------------------------------------------------------------
// LDS layout per tile (bw2/fallback): row*64 bf16; 16B granule slot g of row r
// holds global granule g^(r&7) -> fragment ds_read_b128 aliases 2-way (free).
// Measured: SQ_LDS_BANK_CONFLICT == 0 with this scheme.
// ---------------------------------------------------------------------------

// 128x128 4-wave phase (fallback): acc[4][4], waves 2x2 of 64x64
DEVI void mfma_phase(const u16* As, const u16* Bs, f32x4 acc[4][4])
{
  const int lane = threadIdx.x & 63;
  const int w    = threadIdx.x >> 6;
  const int l16  = lane & 15, lq = lane >> 4;
  const int wm   = (w >> 1) * 64, wn = (w & 1) * 64;
#pragma unroll
  for (int kc = 0; kc < 2; kc++) {
    short8 afr[4], bfr[4];
#pragma unroll
    for (int rt = 0; rt < 4; rt++) {
      int m  = wm + rt * 16 + l16;
      int gr = (kc * 4 + lq) ^ (m & 7);
      afr[rt] = *(const short8*)(As + m * 64 + gr * 8);
    }
#pragma unroll
    for (int ct = 0; ct < 4; ct++) {
      int n  = wn + ct * 16 + l16;
      int gr = (kc * 4 + lq) ^ (n & 7);
      bfr[ct] = *(const short8*)(Bs + n * 64 + gr * 8);
    }
#pragma unroll
    for (int rt = 0; rt < 4; rt++)
#pragma unroll
      for (int ct = 0; ct < 4; ct++)
        acc[rt][ct] = __builtin_amdgcn_mfma_f32_16x16x32_bf16(afr[rt], bfr[ct], acc[rt][ct], 0, 0, 0);
  }
}

// 64x64 4-wave phase (bw2): acc[2][2], waves 2x2 of 32x32
DEVI void mfma_phase32(const u16* As, const u16* Bs, f32x4 acc[2][2])
{
  const int lane = threadIdx.x & 63;
  const int w    = threadIdx.x >> 6;
  const int l16  = lane & 15, lq = lane >> 4;
  const int wm   = (w >> 1) * 32, wn = (w & 1) * 32;
#pragma unroll
  for (int kc = 0; kc < 2; kc++) {
    short8 afr[2], bfr[2];
#pragma unroll
    for (int rt = 0; rt < 2; rt++) {
      int m  = wm + rt * 16 + l16;
      int gr = (kc * 4 + lq) ^ (m & 7);
      afr[rt] = *(const short8*)(As + m * 64 + gr * 8);
    }
#pragma unroll
    for (int ct = 0; ct < 2; ct++) {
      int n  = wn + ct * 16 + l16;
      int gr = (kc * 4 + lq) ^ (n & 7);
      bfr[ct] = *(const short8*)(Bs + n * 64 + gr * 8);
    }
#pragma unroll
    for (int rt = 0; rt < 2; rt++)
#pragma unroll
      for (int ct = 0; ct < 2; ct++)
        acc[rt][ct] = __builtin_amdgcn_mfma_f32_16x16x32_bf16(afr[rt], bfr[ct], acc[rt][ct], 0, 0, 0);
  }
}

DEVI void zero_acc(f32x4 acc[4][4]) {
  f32x4 z = {0.f, 0.f, 0.f, 0.f};
#pragma unroll
  for (int a = 0; a < 4; a++)
#pragma unroll
    for (int b = 0; b < 4; b++) acc[a][b] = z;
}

DEVI void zero_acc22(f32x4 acc[2][2]) {
  f32x4 z = {0.f, 0.f, 0.f, 0.f};
#pragma unroll
  for (int a = 0; a < 2; a++)
#pragma unroll
    for (int b = 0; b < 2; b++) acc[a][b] = z;
}

DEVI void zero_acc24(f32x4 acc[2][4]) {
  f32x4 z = {0.f, 0.f, 0.f, 0.f};
#pragma unroll
  for (int a = 0; a < 2; a++)
#pragma unroll
    for (int b = 0; b < 4; b++) acc[a][b] = z;
}

struct Params {
  const float *x_input, *y_target, *j1, *v1, *s1, *x1, *j2, *v2, *s2, *x2;
  const float *W0, *W1, *W2, *V0, *V1, *V2, *Eg0, *Eg1, *Ed1, *Ed2;
};

// ===========================================================================
// FAST PATH
// ===========================================================================

// async-DMA stage of one (RR*32)x64 bf16 tile; swizzle applied on the GLOBAL
// fetch address (LDS dest of global_load_lds is fixed: base + lane*16B).
template <int RR>
DEVI void stage_async(const u16* gbase, int ldr, int k0, u16* lds)
{
  const int t = threadIdx.x;
  const int lane = t & 63, w = t >> 6;
#pragma unroll
  for (int tt = 0; tt < RR; tt++) {
    int rowbase = w * (RR * 8) + tt * 8;
    int row = rowbase + (lane >> 3);
    int gsw = (lane & 7) ^ (row & 7);
    __builtin_amdgcn_global_load_lds(
        (global_cvoid*)(gbase + (size_t)row * ldr + k0 + gsw * 8),
        (lds_void*)(lds + rowbase * 64), 16, 0, 0);
  }
}

// simple 2-barrier 64x64 term (bw2)
DEVI void gemm_term64(const u16* A, const u16* B, int K,
                      u16* As, u16* Bs, f32x4 acc[2][2])
{
  for (int k0 = 0; k0 < K; k0 += 64) {
    stage_async<2>(A, K, k0, As);
    stage_async<2>(B, K, k0, Bs);
    __syncthreads();
    mfma_phase32(As, Bs, acc);
    __syncthreads();
  }
}

// ---------------------------------------------------------------------------
// barrier-free direct-global 64x128 term (k_main): both TN fragments are
// contiguous 16B per lane, so each wave streams short8 loads straight from
// L2/L3 (ws fits L3) and chains MFMAs with NO __syncthreads / LDS at all.
// One load instruction touches 16 full 64B lines (l16 rows x lq 64B-contig).
// K-accumulation order identical to the LDS version (k ascending, 32-chunks).
// ---------------------------------------------------------------------------
DEVI void gemm_term_direct(const u16* A, const u16* B, int K, f32x4 acc[2][4])
{
  const int lane = threadIdx.x & 63;
  const int w    = threadIdx.x >> 6;
  const int l16  = lane & 15, lq = lane >> 4;
  const int wm   = (w >> 1) * 32, wn = (w & 1) * 64;
  const u16* pa0 = A + (size_t)(wm +  0 + l16) * K + lq * 8;
  const u16* pa1 = A + (size_t)(wm + 16 + l16) * K + lq * 8;
  const u16* pb0 = B + (size_t)(wn +  0 + l16) * K + lq * 8;
  const u16* pb1 = B + (size_t)(wn + 16 + l16) * K + lq * 8;
  const u16* pb2 = B + (size_t)(wn + 32 + l16) * K + lq * 8;
  const u16* pb3 = B + (size_t)(wn + 48 + l16) * K + lq * 8;
  const int nk = K >> 5;
#pragma unroll 4
  for (int kc = 0; kc < nk; kc++) {
    int ko = kc * 32;
    short8 afr[2], bfr[4];
    afr[0] = *(const short8*)(pa0 + ko);
    afr[1] = *(const short8*)(pa1 + ko);
    bfr[0] = *(const short8*)(pb0 + ko);
    bfr[1] = *(const short8*)(pb1 + ko);
    bfr[2] = *(const short8*)(pb2 + ko);
    bfr[3] = *(const short8*)(pb3 + ko);
#pragma unroll
    for (int rt = 0; rt < 2; rt++)
#pragma unroll
      for (int ct = 0; ct < 4; ct++)
        acc[rt][ct] = __builtin_amdgcn_mfma_f32_16x16x32_bf16(afr[rt], bfr[ct], acc[rt][ct], 0, 0, 0);
  }
}

// ---------------------------------------------------------------------------
// k_prep: blocks [0,14464): fp32->bf16 convert (+optional add), 2048 elem/blk
//         blocks [14464,15616): 32x32 transpose tiles W0/V1/W1/V2 -> bf16
// ---------------------------------------------------------------------------
struct PJob { const float *s0, *s1; u16* dst; int start; };
struct TJob { const float* in; u16* out; int J, tbase; };
struct PrepArgs { PJob jb[14]; TJob tj[4]; };

__global__ __launch_bounds__(256) void k_prep(PrepArgs A)
{
  __shared__ u16 T[32][33];
  int b = blockIdx.x;
  int t = threadIdx.x;
  if (b < 14464) {
    int ji = 0;
#pragma unroll
    for (int i = 1; i < 14; i++)
      if (b >= A.jb[i].start) ji = i;
    PJob pj = A.jb[ji];
    size_t e0 = ((size_t)(b - pj.start) * 256 + t) * 8;
    const float* s0 = pj.s0 + e0;
    f32x4 a  = *(const f32x4*)s0;
    f32x4 b4 = *(const f32x4*)(s0 + 4);
    if (pj.s1) {
      const float* s1 = pj.s1 + e0;
      a  = a  + *(const f32x4*)s1;
      b4 = b4 + *(const f32x4*)(s1 + 4);
    }
    *(short8*)(pj.dst + e0) = pack8(a, b4);
    return;
  }
  // transpose tiles: in fp32 [J,512] -> out bf16 [512,J]
  int b2 = b - 14464;
  int ji = 0;
#pragma unroll
  for (int i = 1; i < 4; i++)
    if (b2 >= A.tj[i].tbase) ji = i;
  TJob jb = A.tj[ji];
  int local = b2 - jb.tbase;
  int tm = local >> 4;          // J/32 tile rows
  int tk = local & 15;          // 512/32 tile cols
  int tx = t & 31, ty = t >> 5; // ty 0..7
#pragma unroll
  for (int i = 0; i < 4; i++) {
    int r = ty + i * 8;
    T[r][tx] = f2bf(jb.in[(size_t)(tm * 32 + r) * 512 + tk * 32 + tx]);
  }
  __syncthreads();
#pragma unroll
  for (int i = 0; i < 4; i++) {
    int r = ty + i * 8;
    jb.out[(size_t)(tk * 32 + r) * jb.J + tm * 32 + tx] = T[tx][r];
  }
}

// ---------------------------------------------------------------------------
// k_bw2: Bw1 = -(Eg0@W0 + Ed1@V1), Bw2 = -(Eg1@W1 + Ed2@V2)  [512,512] bf16,
// TN form from pre-converted/transposed bf16 operands. 64x64 tiles, 128 blks.
// ---------------------------------------------------------------------------
struct BW2Args {
  const u16 *Eg0b, *W0tb, *Ed1b, *V1tb, *Eg1b, *W1tb, *Ed2b, *V2tb;
  u16 *Bw1b, *Bw2b;
};

__global__ __launch_bounds__(256) void k_bw2(BW2Args A)
{
  __shared__ u16 As[64 * 64];
  __shared__ u16 Bs[64 * 64];
  int b   = blockIdx.x;
  int mat = b >> 6, loc = b & 63;
  int bmw = loc >> 3, bnw = loc & 7;

  f32x4 acc[2][2];
  zero_acc22(acc);
  u16* dst;
  if (mat == 0) {
    gemm_term64(A.Eg0b + (size_t)bmw * 64 * 1024, A.W0tb + (size_t)bnw * 64 * 1024, 1024, As, Bs, acc);
    gemm_term64(A.Ed1b + (size_t)bmw * 64 * 512,  A.V1tb + (size_t)bnw * 64 * 512,   512, As, Bs, acc);
    dst = A.Bw1b;
  } else {
    gemm_term64(A.Eg1b + (size_t)bmw * 64 * 512,  A.W1tb + (size_t)bnw * 64 * 512,   512, As, Bs, acc);
    gemm_term64(A.Ed2b + (size_t)bmw * 64 * 256,  A.V2tb + (size_t)bnw * 64 * 256,   256, As, Bs, acc);
    dst = A.Bw2b;
  }
  const int lane = threadIdx.x & 63;
  const int w    = threadIdx.x >> 6;
  const int l16  = lane & 15, lq = lane >> 4;
  const int wm   = (w >> 1) * 32, wn = (w & 1) * 32;
#pragma unroll
  for (int rt = 0; rt < 2; rt++)
#pragma unroll
    for (int ct = 0; ct < 2; ct++)
#pragma unroll
      for (int i = 0; i < 4; i++) {
        int rl = wm + rt * 16 + lq * 4 + i;
        int cl = wn + ct * 16 + l16;
        dst[(size_t)(bmw * 64 + rl) * 512 + bnw * 64 + cl] = f2bf(-acc[rt][ct][i]);
      }
}

// ---------------------------------------------------------------------------
// k_main_fast: 64x128 output tiles (1024 blocks), per layer total = 4 TN GEMM
// terms computed BARRIER-FREE from global (no LDS), fused LIF epilogue.
// ---------------------------------------------------------------------------
struct MJobF {
  const u16* A[4]; const u16* B[4]; int K[4];
  const float *jin, *vin, *xin;
  int obase;
};
struct MArgsF { MJobF j[2]; };

__global__ __launch_bounds__(256, 4) void k_main_fast(MArgsF P, float* __restrict__ out)
{
  int bid   = blockIdx.x;
  int job   = bid >> 9;
  int local = bid & 511;
  int bm = local & 127, bn = local >> 7;
  MJobF jb = P.j[job];

  // spread the initial load burst across co-resident blocks
  switch (((bid >> 8) ^ bid) & 3) {
    case 1: __builtin_amdgcn_s_sleep(8); break;
    case 2: __builtin_amdgcn_s_sleep(8); __builtin_amdgcn_s_sleep(8); break;
    case 3: __builtin_amdgcn_s_sleep(8); __builtin_amdgcn_s_sleep(8);
            __builtin_amdgcn_s_sleep(8); break;
    default: break;
  }

  f32x4 acc[2][4];
  zero_acc24(acc);
#pragma unroll
  for (int p = 0; p < 4; p++)
    gemm_term_direct(jb.A[p] + (size_t)bm * 64 * jb.K[p],
                     jb.B[p] + (size_t)bn * 128 * jb.K[p], jb.K[p], acc);

  const int lane = threadIdx.x & 63;
  const int w    = threadIdx.x >> 6;
  const int l16  = lane & 15, lq = lane >> 4;
  const int wm   = (w >> 1) * 32, wn = (w & 1) * 64;

#pragma unroll
  for (int rt = 0; rt < 2; rt++)
#pragma unroll
    for (int ct = 0; ct < 4; ct++)
#pragma unroll
      for (int i = 0; i < 4; i++) {
        int row    = bm * 64 + wm + rt * 16 + lq * 4 + i;
        int col    = bn * 128 + wn + ct * 16 + l16;
        size_t idx = (size_t)row * 512 + col;
        float xf = jb.xin[idx];
        float total = acc[rt][ct][i] - 2.0f * xf;
        float jf = jb.jin[idx];
        float vf = jb.vin[idx];
        jf = jf + 0.1f * (-0.25f * jf + total);
        vf = vf + 0.05f * (-vf + jf);
        float sf = (vf > 0.4f) ? 1.0f : 0.0f;
        vf = vf * (1.0f - sf);
        xf = xf + (-xf / 20.0f + sf);
        size_t ob = (size_t)row * 4096 + jb.obase + col;
        out[ob]        = jf;
        out[ob + 512]  = vf;
        out[ob + 1024] = xf;
        out[ob + 1536] = sf;
      }
}

// ===========================================================================
// FALLBACK PATH (verbatim; used only if ws too small)
// ===========================================================================

DEVI void stage_A_fb(const float* A, int ldr, int k0, u16* dst)
{
  const int t = threadIdx.x;
  const int g = t & 7, rb = t >> 3;
#pragma unroll
  for (int p = 0; p < 4; p++) {
    int row = p * 32 + rb;
    const float* src = A + (size_t)row * ldr + k0 + g * 8;
    f32x4 a = *(const f32x4*)src;
    f32x4 b = *(const f32x4*)(src + 4);
    *(short8*)(dst + row * 64 + (g ^ (row & 7)) * 8) = pack8(a, b);
  }
}

DEVI void nn_term_fb(const float* A, const float* B, int K, u16* As, u16* Bs, f32x4 acc[4][4])
{
  const int t  = threadIdx.x;
  const int ks = t >> 4, ng = t & 15;
  for (int k0 = 0; k0 < K; k0 += 64) {
    stage_A_fb(A, K, k0, As);
#pragma unroll
    for (int i = 0; i < 4; i++) {
      int kloc = i * 16 + ks;
      const float* src = B + (size_t)(k0 + kloc) * 512 + ng * 8;
      f32x4 a = *(const f32x4*)src;
      f32x4 b = *(const f32x4*)(src + 4);
#pragma unroll
      for (int e = 0; e < 8; e++) {
        int nloc = ng * 8 + e;
        float val = (e < 4) ? a[e] : b[e - 4];
        Bs[nloc * 64 + ((kloc >> 3) ^ (nloc & 7)) * 8 + (kloc & 7)] = f2bf(val);
      }
    }
    __syncthreads();
    mfma_phase(As, Bs, acc);
    __syncthreads();
  }
}

template <int MODE>
DEVI void gemm_term_fb(const float* A, const float* B0, const float* B1, int K,
                       u16* As, u16* Bs, f32x4 acc[4][4])
{
  const int t = threadIdx.x;
  const int g = t & 7, rb = t >> 3;
  for (int k0 = 0; k0 < K; k0 += 64) {
    stage_A_fb(A, K, k0, As);
#pragma unroll
    for (int p = 0; p < 4; p++) {
      int row = p * 32 + rb;
      const float* src;
      if (MODE == 2) src = B0 + (size_t)row * 4096 + (k0 >> 7) * 512 + (k0 & 127) + g * 8;
      else           src = B0 + (size_t)row * K + k0 + g * 8;
      f32x4 a = *(const f32x4*)src;
      f32x4 b = *(const f32x4*)(src + 4);
      if (MODE == 1) {
        const float* s2 = B1 + (size_t)row * K + k0 + g * 8;
        a = a + *(const f32x4*)s2;
        b = b + *(const f32x4*)(s2 + 4);
      }
      *(short8*)(Bs + row * 64 + (g ^ (row & 7)) * 8) = pack8(a, b);
    }
    __syncthreads();
    mfma_phase(As, Bs, acc);
    __syncthreads();
  }
}

__global__ __launch_bounds__(256) void k_bw_fb(Params P, float* __restrict__ out)
{
  __shared__ u16 As[128 * 64];
  __shared__ u16 Bs[128 * 64];
  int b   = blockIdx.x;
  int mat = b >> 4, loc = b & 15;
  int bmw = loc >> 2, bnw = loc & 3;

  f32x4 acc[4][4];
  zero_acc(acc);
  int obase;
  if (mat == 0) {
    nn_term_fb(P.Eg0 + (size_t)bmw * 128 * 1024, P.W0 + bnw * 128, 1024, As, Bs, acc);
    nn_term_fb(P.Ed1 + (size_t)bmw * 128 * 512,  P.V1 + bnw * 128,  512, As, Bs, acc);
    obase = 0;
  } else {
    nn_term_fb(P.Eg1 + (size_t)bmw * 128 * 512,  P.W1 + bnw * 128,  512, As, Bs, acc);
    nn_term_fb(P.Ed2 + (size_t)bmw * 128 * 256,  P.V2 + bnw * 128,  256, As, Bs, acc);
    obase = 2048;
  }
  const int lane = threadIdx.x & 63;
  const int w    = threadIdx.x >> 6;
  const int l16  = lane & 15, lq = lane >> 4;
  const int wm   = (w >> 1) * 64, wn = (w & 1) * 64;
#pragma unroll
  for (int rt = 0; rt < 4; rt++)
#pragma unroll
    for (int ct = 0; ct < 4; ct++)
#pragma unroll
      for (int i = 0; i < 4; i++) {
        int rl = wm + rt * 16 + lq * 4 + i;
        int cl = wn + ct * 16 + l16;
        out[(size_t)rl * 4096 + obase + bmw * 128 + bnw * 512 + cl] = -acc[rt][ct][i];
      }
}

__global__ __launch_bounds__(256) void k_main_fb(Params P, float* __restrict__ out, int fix)
{
  __shared__ u16 As[128 * 64];
  __shared__ u16 Bs[128 * 64];
  int job, bm, bn;
  if (fix) {
    job = blockIdx.x >> 2; bn = blockIdx.x & 3; bm = 0;
  } else {
    job = blockIdx.x >> 8;
    int local = blockIdx.x & 255;
    bm = local & 63; bn = local >> 6;
    if (bm == 0) return;
  }

  f32x4 acc[4][4];
  zero_acc(acc);
  const float *jin, *vin, *xin;
  int obase;
  size_t am = (size_t)bm * 128;

  if (job == 0) {
    gemm_term_fb<0>(P.s2      + am * 512,  P.W1  + (size_t)bn * 128 * 512,  nullptr, 512,  As, Bs, acc);
    gemm_term_fb<1>(P.x_input + am * 1024, P.V0  + (size_t)bn * 128 * 1024,
                    P.Eg0 + (size_t)bn * 128 * 1024, 1024, As, Bs, acc);
    gemm_term_fb<0>(P.x2      + am * 512,  P.Ed1 + (size_t)bn * 128 * 512,  nullptr, 512,  As, Bs, acc);
    gemm_term_fb<2>(P.s1      + am * 512,  out + 0 + bn * 128,              nullptr, 512,  As, Bs, acc);
    jin = P.j1; vin = P.v1; xin = P.x1; obase = 0;
  } else {
    gemm_term_fb<1>(P.y_target + am * 256, P.W2  + (size_t)bn * 128 * 256,
                    P.Ed2 + (size_t)bn * 128 * 256, 256, As, Bs, acc);
    gemm_term_fb<0>(P.s1      + am * 512,  P.V1  + (size_t)bn * 128 * 512,  nullptr, 512,  As, Bs, acc);
    gemm_term_fb<0>(P.x1      + am * 512,  P.Eg1 + (size_t)bn * 128 * 512,  nullptr, 512,  As, Bs, acc);
    gemm_term_fb<2>(P.s2      + am * 512,  out + 2048 + bn * 128,           nullptr, 512,  As, Bs, acc);
    jin = P.j2; vin = P.v2; xin = P.x2; obase = 2048;
  }

  const int lane = threadIdx.x & 63;
  const int w    = threadIdx.x >> 6;
  const int l16  = lane & 15, lq = lane >> 4;
  const int wm   = (w >> 1) * 64, wn = (w & 1) * 64;

#pragma unroll
  for (int rt = 0; rt < 4; rt++)
#pragma unroll
    for (int ct = 0; ct < 4; ct++)
#pragma unroll
      for (int i = 0; i < 4; i++) {
        int row    = bm * 128 + wm + rt * 16 + lq * 4 + i;
        int col    = bn * 128 + wn + ct * 16 + l16;
        size_t idx = (size_t)row * 512 + col;
        float xf = xin[idx];
        float total = acc[rt][ct][i] - 2.0f * xf;
        float jf = jin[idx];
        float vf = vin[idx];
        jf = jf + 0.1f * (-0.25f * jf + total);
        vf = vf + 0.05f * (-vf + jf);
        float sf = (vf > 0.4f) ? 1.0f : 0.0f;
        vf = vf * (1.0f - sf);
        xf = xf + (-xf / 20.0f + sf);
        size_t ob = (size_t)row * 4096 + obase + col;
        out[ob]        = jf;
        out[ob + 512]  = vf;
        out[ob + 1024] = xf;
        out[ob + 1536] = sf;
      }
}

// ---------------------------------------------------------------------------
extern "C" void kernel_launch(void* const* d_in, const int* in_sizes, int n_in,
                              void* d_out, int out_size, void* d_ws, size_t ws_size,
                              hipStream_t stream)
{
  Params P;
  P.x_input  = (const float*)d_in[0];
  P.y_target = (const float*)d_in[1];
  P.j1 = (const float*)d_in[2];
  P.v1 = (const float*)d_in[3];
  P.s1 = (const float*)d_in[4];
  P.x1 = (const float*)d_in[5];
  P.j2 = (const float*)d_in[6];
  P.v2 = (const float*)d_in[7];
  P.s2 = (const float*)d_in[8];
  P.x2 = (const float*)d_in[9];
  P.W0 = (const float*)d_in[10];
  P.W1 = (const float*)d_in[11];
  P.W2 = (const float*)d_in[12];
  P.V0 = (const float*)d_in[13];
  P.V1 = (const float*)d_in[14];
  P.V2 = (const float*)d_in[15];
  P.Eg0 = (const float*)d_in[16];
  P.Eg1 = (const float*)d_in[17];
  P.Ed1 = (const float*)d_in[20];
  P.Ed2 = (const float*)d_in[21];
  (void)in_sizes; (void)n_in; (void)out_size;

  float* out = (float*)d_out;

  if (ws_size >= 62652416) {
    char* ws = (char*)d_ws;
    u16* xin_b = (u16*)(ws + 0);         // [8192,1024]
    u16* y_b   = (u16*)(ws + 16777216);  // [8192,256]
    u16* s1_b  = (u16*)(ws + 20971520);  // [8192,512]
    u16* x1_b  = (u16*)(ws + 29360128);
    u16* s2_b  = (u16*)(ws + 37748736);
    u16* x2_b  = (u16*)(ws + 46137344);
    u16* W1_b  = (u16*)(ws + 54525952);  // [512,512]
    u16* P1_b  = (u16*)(ws + 55050240);  // [512,1024] = V0+Eg0
    u16* Ed1_b = (u16*)(ws + 56098816);  // [512,512]
    u16* V1_b  = (u16*)(ws + 56623104);
    u16* Eg1_b = (u16*)(ws + 57147392);
    u16* P2_b  = (u16*)(ws + 57671680);  // [512,256] = W2+Ed2
    u16* Bw1_b = (u16*)(ws + 57933824);  // [512,512]
    u16* Bw2_b = (u16*)(ws + 58458112);  // [512,512]
    u16* W0t_b = (u16*)(ws + 58982400);  // [512,1024]
    u16* V1t_b = (u16*)(ws + 60030976);  // [512,512]
    u16* W1t_b = (u16*)(ws + 60555264);  // [512,512]
    u16* V2t_b = (u16*)(ws + 61079552);  // [512,256]
    u16* Eg0_b = (u16*)(ws + 61341696);  // [512,1024]
    u16* Ed2_b = (u16*)(ws + 62390272);  // [512,256]  (end 62652416)

    PrepArgs pa;
    pa.jb[0]  = { P.x_input,  nullptr, xin_b,     0 };
    pa.jb[1]  = { P.y_target, nullptr, y_b,    4096 };
    pa.jb[2]  = { P.s1,       nullptr, s1_b,   5120 };
    pa.jb[3]  = { P.x1,       nullptr, x1_b,   7168 };
    pa.jb[4]  = { P.s2,       nullptr, s2_b,   9216 };
    pa.jb[5]  = { P.x2,       nullptr, x2_b,  11264 };
    pa.jb[6]  = { P.W1,       nullptr, W1_b,  13312 };
    pa.jb[7]  = { P.V0,       P.Eg0,   P1_b,  13440 };
    pa.jb[8]  = { P.Ed1,      nullptr, Ed1_b, 13696 };
    pa.jb[9]  = { P.V1,       nullptr, V1_b,  13824 };
    pa.jb[10] = { P.Eg1,      nullptr, Eg1_b, 13952 };
    pa.jb[11] = { P.W2,       P.Ed2,   P2_b,  14080 };
    pa.jb[12] = { P.Eg0,      nullptr, Eg0_b, 14144 };
    pa.jb[13] = { P.Ed2,      nullptr, Ed2_b, 14400 };   // 64 blocks -> 14464
    pa.tj[0]  = { P.W0, W0t_b, 1024,    0 };   // 512 tiles
    pa.tj[1]  = { P.V1, V1t_b,  512,  512 };   // 256
    pa.tj[2]  = { P.W1, W1t_b,  512,  768 };   // 256
    pa.tj[3]  = { P.V2, V2t_b,  256, 1024 };   // 128 -> 1152
    k_prep<<<dim3(15616), dim3(256), 0, stream>>>(pa);

    BW2Args ba;
    ba.Eg0b = Eg0_b; ba.W0tb = W0t_b; ba.Ed1b = Ed1_b; ba.V1tb = V1t_b;
    ba.Eg1b = Eg1_b; ba.W1tb = W1t_b; ba.Ed2b = Ed2_b; ba.V2tb = V2t_b;
    ba.Bw1b = Bw1_b; ba.Bw2b = Bw2_b;
    k_bw2<<<dim3(128), dim3(256), 0, stream>>>(ba);

    MArgsF ma;
    ma.j[0].A[0] = s2_b;  ma.j[0].B[0] = W1_b;  ma.j[0].K[0] = 512;
    ma.j[0].A[1] = xin_b; ma.j[0].B[1] = P1_b;  ma.j[0].K[1] = 1024;
    ma.j[0].A[2] = x2_b;  ma.j[0].B[2] = Ed1_b; ma.j[0].K[2] = 512;
    ma.j[0].A[3] = s1_b;  ma.j[0].B[3] = Bw1_b; ma.j[0].K[3] = 512;
    ma.j[0].jin = P.j1; ma.j[0].vin = P.v1; ma.j[0].xin = P.x1; ma.j[0].obase = 0;
    ma.j[1].A[0] = y_b;   ma.j[1].B[0] = P2_b;  ma.j[1].K[0] = 256;
    ma.j[1].A[1] = s1_b;  ma.j[1].B[1] = V1_b;  ma.j[1].K[1] = 512;
    ma.j[1].A[2] = x1_b;  ma.j[1].B[2] = Eg1_b; ma.j[1].K[2] = 512;
    ma.j[1].A[3] = s2_b;  ma.j[1].B[3] = Bw2_b; ma.j[1].K[3] = 512;
    ma.j[1].jin = P.j2; ma.j[1].vin = P.v2; ma.j[1].xin = P.x2; ma.j[1].obase = 2048;
    k_main_fast<<<dim3(1024), dim3(256), 0, stream>>>(ma, out);
  } else {
    k_bw_fb<<<dim3(32), dim3(256), 0, stream>>>(P, out);
    k_main_fb<<<dim3(512), dim3(256), 0, stream>>>(P, out, 0);
    k_main_fb<<<dim3(8), dim3(256), 0, stream>>>(P, out, 1);
  }
}

// Round 7
// 418.967 us; speedup vs baseline: 1.2841x; 1.2841x over previous
//
#include <hip/hip_runtime.h>
#include <stdint.h>
#include <stddef.h>

typedef unsigned short u16;
typedef __attribute__((ext_vector_type(8))) short short8;
typedef __attribute__((ext_vector_type(4))) float f32x4;

#define DEVI __device__ __forceinline__

DEVI u16 f2bf(float f) {
  union { float f; unsigned u; } c; c.f = f;
  unsigned r = c.u + 0x7fff + ((c.u >> 16) & 1);
  return (u16)(r >> 16);
}

DEVI short8 pack8(f32x4 a, f32x4 b) {
  short8 v;
#pragma unroll
  for (int i = 0; i < 4; i++) { v[i] = (short)f2bf(a[i]); v[i + 4] = (short)f2bf(b[i]); }
  return v;
}

typedef __attribute__((address_space(1))) const void global_cvoid;
typedef __attribute__((address_space(3))) void lds_void;

// ---------------------------------------------------------------------------
// LDS layout per tile: row*64 bf16; 16B granule slot g of row r holds global
// granule g^(r&7) -> fragment ds_read_b128 aliases 2-way (free).
// Measured: SQ_LDS_BANK_CONFLICT == 0 with this scheme.
// ---------------------------------------------------------------------------

// 128x128 4-wave phase (fallback): acc[4][4], waves 2x2 of 64x64
DEVI void mfma_phase(const u16* As, const u16* Bs, f32x4 acc[4][4])
{
  const int lane = threadIdx.x & 63;
  const int w    = threadIdx.x >> 6;
  const int l16  = lane & 15, lq = lane >> 4;
  const int wm   = (w >> 1) * 64, wn = (w & 1) * 64;
#pragma unroll
  for (int kc = 0; kc < 2; kc++) {
    short8 afr[4], bfr[4];
#pragma unroll
    for (int rt = 0; rt < 4; rt++) {
      int m  = wm + rt * 16 + l16;
      int gr = (kc * 4 + lq) ^ (m & 7);
      afr[rt] = *(const short8*)(As + m * 64 + gr * 8);
    }
#pragma unroll
    for (int ct = 0; ct < 4; ct++) {
      int n  = wn + ct * 16 + l16;
      int gr = (kc * 4 + lq) ^ (n & 7);
      bfr[ct] = *(const short8*)(Bs + n * 64 + gr * 8);
    }
#pragma unroll
    for (int rt = 0; rt < 4; rt++)
#pragma unroll
      for (int ct = 0; ct < 4; ct++)
        acc[rt][ct] = __builtin_amdgcn_mfma_f32_16x16x32_bf16(afr[rt], bfr[ct], acc[rt][ct], 0, 0, 0);
  }
}

// 64x64 4-wave phase (bw2): acc[2][2], waves 2x2 of 32x32
DEVI void mfma_phase32(const u16* As, const u16* Bs, f32x4 acc[2][2])
{
  const int lane = threadIdx.x & 63;
  const int w    = threadIdx.x >> 6;
  const int l16  = lane & 15, lq = lane >> 4;
  const int wm   = (w >> 1) * 32, wn = (w & 1) * 32;
#pragma unroll
  for (int kc = 0; kc < 2; kc++) {
    short8 afr[2], bfr[2];
#pragma unroll
    for (int rt = 0; rt < 2; rt++) {
      int m  = wm + rt * 16 + l16;
      int gr = (kc * 4 + lq) ^ (m & 7);
      afr[rt] = *(const short8*)(As + m * 64 + gr * 8);
    }
#pragma unroll
    for (int ct = 0; ct < 2; ct++) {
      int n  = wn + ct * 16 + l16;
      int gr = (kc * 4 + lq) ^ (n & 7);
      bfr[ct] = *(const short8*)(Bs + n * 64 + gr * 8);
    }
#pragma unroll
    for (int rt = 0; rt < 2; rt++)
#pragma unroll
      for (int ct = 0; ct < 2; ct++)
        acc[rt][ct] = __builtin_amdgcn_mfma_f32_16x16x32_bf16(afr[rt], bfr[ct], acc[rt][ct], 0, 0, 0);
  }
}

// 64x128 4-wave phase (main): acc[2][4], waves 2x2 of 32x64
DEVI void mfma_phase64(const u16* As, const u16* Bs, f32x4 acc[2][4])
{
  const int lane = threadIdx.x & 63;
  const int w    = threadIdx.x >> 6;
  const int l16  = lane & 15, lq = lane >> 4;
  const int wm   = (w >> 1) * 32, wn = (w & 1) * 64;
#pragma unroll
  for (int kc = 0; kc < 2; kc++) {
    short8 afr[2], bfr[4];
#pragma unroll
    for (int rt = 0; rt < 2; rt++) {
      int m  = wm + rt * 16 + l16;
      int gr = (kc * 4 + lq) ^ (m & 7);
      afr[rt] = *(const short8*)(As + m * 64 + gr * 8);
    }
#pragma unroll
    for (int ct = 0; ct < 4; ct++) {
      int n  = wn + ct * 16 + l16;
      int gr = (kc * 4 + lq) ^ (n & 7);
      bfr[ct] = *(const short8*)(Bs + n * 64 + gr * 8);
    }
#pragma unroll
    for (int rt = 0; rt < 2; rt++)
#pragma unroll
      for (int ct = 0; ct < 4; ct++)
        acc[rt][ct] = __builtin_amdgcn_mfma_f32_16x16x32_bf16(afr[rt], bfr[ct], acc[rt][ct], 0, 0, 0);
  }
}

DEVI void zero_acc(f32x4 acc[4][4]) {
  f32x4 z = {0.f, 0.f, 0.f, 0.f};
#pragma unroll
  for (int a = 0; a < 4; a++)
#pragma unroll
    for (int b = 0; b < 4; b++) acc[a][b] = z;
}

DEVI void zero_acc22(f32x4 acc[2][2]) {
  f32x4 z = {0.f, 0.f, 0.f, 0.f};
#pragma unroll
  for (int a = 0; a < 2; a++)
#pragma unroll
    for (int b = 0; b < 2; b++) acc[a][b] = z;
}

DEVI void zero_acc24(f32x4 acc[2][4]) {
  f32x4 z = {0.f, 0.f, 0.f, 0.f};
#pragma unroll
  for (int a = 0; a < 2; a++)
#pragma unroll
    for (int b = 0; b < 4; b++) acc[a][b] = z;
}

struct Params {
  const float *x_input, *y_target, *j1, *v1, *s1, *x1, *j2, *v2, *s2, *x2;
  const float *W0, *W1, *W2, *V0, *V1, *V2, *Eg0, *Eg1, *Ed1, *Ed2;
};

// ===========================================================================
// FAST PATH
// ===========================================================================

// async-DMA stage of one (RR*32)x64 bf16 tile; swizzle applied on the GLOBAL
// fetch address (LDS dest of global_load_lds is fixed: base + lane*16B).
template <int RR>
DEVI void stage_async(const u16* gbase, int ldr, int k0, u16* lds)
{
  const int t = threadIdx.x;
  const int lane = t & 63, w = t >> 6;
#pragma unroll
  for (int tt = 0; tt < RR; tt++) {
    int rowbase = w * (RR * 8) + tt * 8;
    int row = rowbase + (lane >> 3);
    int gsw = (lane & 7) ^ (row & 7);
    __builtin_amdgcn_global_load_lds(
        (global_cvoid*)(gbase + (size_t)row * ldr + k0 + gsw * 8),
        (lds_void*)(lds + rowbase * 64), 16, 0, 0);
  }
}

// simple 2-barrier 64x64 term (bw2)
DEVI void gemm_term64(const u16* A, const u16* B, int K,
                      u16* As, u16* Bs, f32x4 acc[2][2])
{
  for (int k0 = 0; k0 < K; k0 += 64) {
    stage_async<2>(A, K, k0, As);
    stage_async<2>(B, K, k0, Bs);
    __syncthreads();
    mfma_phase32(As, Bs, acc);
    __syncthreads();
  }
}

// ---------------------------------------------------------------------------
// ping-pong 64x128 term (k_main): double-buffered LDS, stage(t+1) issued
// BEFORE mfma(t), ONE __syncthreads per step (vs 2 in the plain loop).
// No inline asm / sched_barrier (r2's confounders). Staging latency hides
// under the same step's ds_read+MFMA; barrier's lgkm drain protects buffer
// reuse at t+2. K-accumulation order unchanged -> bitwise-identical output.
// ---------------------------------------------------------------------------
DEVI void gemm_term_pp(const u16* A, const u16* B, int K,
                       u16* As0, u16* As1, u16* Bs0, u16* Bs1, f32x4 acc[2][4])
{
  const int nk = K >> 6;
  stage_async<2>(A, K, 0, As0);
  stage_async<4>(B, K, 0, Bs0);
  __syncthreads();
  for (int t = 0; t < nk; t++) {
    if (t + 1 < nk) {
      if (t & 1) { stage_async<2>(A, K, (t + 1) * 64, As0); stage_async<4>(B, K, (t + 1) * 64, Bs0); }
      else       { stage_async<2>(A, K, (t + 1) * 64, As1); stage_async<4>(B, K, (t + 1) * 64, Bs1); }
    }
    if (t & 1) mfma_phase64(As1, Bs1, acc);
    else       mfma_phase64(As0, Bs0, acc);
    __syncthreads();
  }
}

// ---------------------------------------------------------------------------
// k_prep: blocks [0,14464): fp32->bf16 convert (+optional add), 2048 elem/blk
//         blocks [14464,15616): 32x32 transpose tiles W0/V1/W1/V2 -> bf16
// ---------------------------------------------------------------------------
struct PJob { const float *s0, *s1; u16* dst; int start; };
struct TJob { const float* in; u16* out; int J, tbase; };
struct PrepArgs { PJob jb[14]; TJob tj[4]; };

__global__ __launch_bounds__(256) void k_prep(PrepArgs A)
{
  __shared__ u16 T[32][33];
  int b = blockIdx.x;
  int t = threadIdx.x;
  if (b < 14464) {
    int ji = 0;
#pragma unroll
    for (int i = 1; i < 14; i++)
      if (b >= A.jb[i].start) ji = i;
    PJob pj = A.jb[ji];
    size_t e0 = ((size_t)(b - pj.start) * 256 + t) * 8;
    const float* s0 = pj.s0 + e0;
    f32x4 a  = *(const f32x4*)s0;
    f32x4 b4 = *(const f32x4*)(s0 + 4);
    if (pj.s1) {
      const float* s1 = pj.s1 + e0;
      a  = a  + *(const f32x4*)s1;
      b4 = b4 + *(const f32x4*)(s1 + 4);
    }
    *(short8*)(pj.dst + e0) = pack8(a, b4);
    return;
  }
  // transpose tiles: in fp32 [J,512] -> out bf16 [512,J]
  int b2 = b - 14464;
  int ji = 0;
#pragma unroll
  for (int i = 1; i < 4; i++)
    if (b2 >= A.tj[i].tbase) ji = i;
  TJob jb = A.tj[ji];
  int local = b2 - jb.tbase;
  int tm = local >> 4;          // J/32 tile rows
  int tk = local & 15;          // 512/32 tile cols
  int tx = t & 31, ty = t >> 5; // ty 0..7
#pragma unroll
  for (int i = 0; i < 4; i++) {
    int r = ty + i * 8;
    T[r][tx] = f2bf(jb.in[(size_t)(tm * 32 + r) * 512 + tk * 32 + tx]);
  }
  __syncthreads();
#pragma unroll
  for (int i = 0; i < 4; i++) {
    int r = ty + i * 8;
    jb.out[(size_t)(tk * 32 + r) * jb.J + tm * 32 + tx] = T[tx][r];
  }
}

// ---------------------------------------------------------------------------
// k_bw2: Bw1 = -(Eg0@W0 + Ed1@V1), Bw2 = -(Eg1@W1 + Ed2@V2)  [512,512] bf16,
// TN form from pre-converted/transposed bf16 operands. 64x64 tiles, 128 blks.
// ---------------------------------------------------------------------------
struct BW2Args {
  const u16 *Eg0b, *W0tb, *Ed1b, *V1tb, *Eg1b, *W1tb, *Ed2b, *V2tb;
  u16 *Bw1b, *Bw2b;
};

__global__ __launch_bounds__(256) void k_bw2(BW2Args A)
{
  __shared__ u16 As[64 * 64];
  __shared__ u16 Bs[64 * 64];
  int b   = blockIdx.x;
  int mat = b >> 6, loc = b & 63;
  int bmw = loc >> 3, bnw = loc & 7;

  f32x4 acc[2][2];
  zero_acc22(acc);
  u16* dst;
  if (mat == 0) {
    gemm_term64(A.Eg0b + (size_t)bmw * 64 * 1024, A.W0tb + (size_t)bnw * 64 * 1024, 1024, As, Bs, acc);
    gemm_term64(A.Ed1b + (size_t)bmw * 64 * 512,  A.V1tb + (size_t)bnw * 64 * 512,   512, As, Bs, acc);
    dst = A.Bw1b;
  } else {
    gemm_term64(A.Eg1b + (size_t)bmw * 64 * 512,  A.W1tb + (size_t)bnw * 64 * 512,   512, As, Bs, acc);
    gemm_term64(A.Ed2b + (size_t)bmw * 64 * 256,  A.V2tb + (size_t)bnw * 64 * 256,   256, As, Bs, acc);
    dst = A.Bw2b;
  }
  const int lane = threadIdx.x & 63;
  const int w    = threadIdx.x >> 6;
  const int l16  = lane & 15, lq = lane >> 4;
  const int wm   = (w >> 1) * 32, wn = (w & 1) * 32;
#pragma unroll
  for (int rt = 0; rt < 2; rt++)
#pragma unroll
    for (int ct = 0; ct < 2; ct++)
#pragma unroll
      for (int i = 0; i < 4; i++) {
        int rl = wm + rt * 16 + lq * 4 + i;
        int cl = wn + ct * 16 + l16;
        dst[(size_t)(bmw * 64 + rl) * 512 + bnw * 64 + cl] = f2bf(-acc[rt][ct][i]);
      }
}

// ---------------------------------------------------------------------------
// k_main_fast: 64x128 output tiles (1024 blocks, 3/CU resident @48KB LDS),
// per layer total = 4 TN GEMM terms (bf16 ws operands), fused LIF epilogue.
// Ping-pong double-buffer, 1 barrier/step. Entry stagger de-convoys blocks.
// ---------------------------------------------------------------------------
struct MJobF {
  const u16* A[4]; const u16* B[4]; int K[4];
  const float *jin, *vin, *xin;
  int obase;
};
struct MArgsF { MJobF j[2]; };

__global__ __launch_bounds__(256, 3) void k_main_fast(MArgsF P, float* __restrict__ out)
{
  __shared__ u16 As0[64 * 64];
  __shared__ u16 As1[64 * 64];
  __shared__ u16 Bs0[128 * 64];
  __shared__ u16 Bs1[128 * 64];
  int bid   = blockIdx.x;
  int job   = bid >> 9;
  int local = bid & 511;
  int bm = local & 127, bn = local >> 7;
  MJobF jb = P.j[job];

  // de-convoy: offset co-resident blocks by ~0/0.5/1/1.5k cycles.
  switch (((bid >> 8) ^ bid) & 3) {
    case 1: __builtin_amdgcn_s_sleep(8); break;
    case 2: __builtin_amdgcn_s_sleep(8); __builtin_amdgcn_s_sleep(8); break;
    case 3: __builtin_amdgcn_s_sleep(8); __builtin_amdgcn_s_sleep(8);
            __builtin_amdgcn_s_sleep(8); break;
    default: break;
  }

  f32x4 acc[2][4];
  zero_acc24(acc);
#pragma unroll
  for (int p = 0; p < 4; p++)
    gemm_term_pp(jb.A[p] + (size_t)bm * 64 * jb.K[p],
                 jb.B[p] + (size_t)bn * 128 * jb.K[p], jb.K[p],
                 As0, As1, Bs0, Bs1, acc);

  const int lane = threadIdx.x & 63;
  const int w    = threadIdx.x >> 6;
  const int l16  = lane & 15, lq = lane >> 4;
  const int wm   = (w >> 1) * 32, wn = (w & 1) * 64;

#pragma unroll
  for (int rt = 0; rt < 2; rt++)
#pragma unroll
    for (int ct = 0; ct < 4; ct++)
#pragma unroll
      for (int i = 0; i < 4; i++) {
        int row    = bm * 64 + wm + rt * 16 + lq * 4 + i;
        int col    = bn * 128 + wn + ct * 16 + l16;
        size_t idx = (size_t)row * 512 + col;
        float xf = jb.xin[idx];
        float total = acc[rt][ct][i] - 2.0f * xf;
        float jf = jb.jin[idx];
        float vf = jb.vin[idx];
        jf = jf + 0.1f * (-0.25f * jf + total);
        vf = vf + 0.05f * (-vf + jf);
        float sf = (vf > 0.4f) ? 1.0f : 0.0f;
        vf = vf * (1.0f - sf);
        xf = xf + (-xf / 20.0f + sf);
        size_t ob = (size_t)row * 4096 + jb.obase + col;
        out[ob]        = jf;
        out[ob + 512]  = vf;
        out[ob + 1024] = xf;
        out[ob + 1536] = sf;
      }
}

// ===========================================================================
// FALLBACK PATH (verbatim; used only if ws too small)
// ===========================================================================

DEVI void stage_A_fb(const float* A, int ldr, int k0, u16* dst)
{
  const int t = threadIdx.x;
  const int g = t & 7, rb = t >> 3;
#pragma unroll
  for (int p = 0; p < 4; p++) {
    int row = p * 32 + rb;
    const float* src = A + (size_t)row * ldr + k0 + g * 8;
    f32x4 a = *(const f32x4*)src;
    f32x4 b = *(const f32x4*)(src + 4);
    *(short8*)(dst + row * 64 + (g ^ (row & 7)) * 8) = pack8(a, b);
  }
}

DEVI void nn_term_fb(const float* A, const float* B, int K, u16* As, u16* Bs, f32x4 acc[4][4])
{
  const int t  = threadIdx.x;
  const int ks = t >> 4, ng = t & 15;
  for (int k0 = 0; k0 < K; k0 += 64) {
    stage_A_fb(A, K, k0, As);
#pragma unroll
    for (int i = 0; i < 4; i++) {
      int kloc = i * 16 + ks;
      const float* src = B + (size_t)(k0 + kloc) * 512 + ng * 8;
      f32x4 a = *(const f32x4*)src;
      f32x4 b = *(const f32x4*)(src + 4);
#pragma unroll
      for (int e = 0; e < 8; e++) {
        int nloc = ng * 8 + e;
        float val = (e < 4) ? a[e] : b[e - 4];
        Bs[nloc * 64 + ((kloc >> 3) ^ (nloc & 7)) * 8 + (kloc & 7)] = f2bf(val);
      }
    }
    __syncthreads();
    mfma_phase(As, Bs, acc);
    __syncthreads();
  }
}

template <int MODE>
DEVI void gemm_term_fb(const float* A, const float* B0, const float* B1, int K,
                       u16* As, u16* Bs, f32x4 acc[4][4])
{
  const int t = threadIdx.x;
  const int g = t & 7, rb = t >> 3;
  for (int k0 = 0; k0 < K; k0 += 64) {
    stage_A_fb(A, K, k0, As);
#pragma unroll
    for (int p = 0; p < 4; p++) {
      int row = p * 32 + rb;
      const float* src;
      if (MODE == 2) src = B0 + (size_t)row * 4096 + (k0 >> 7) * 512 + (k0 & 127) + g * 8;
      else           src = B0 + (size_t)row * K + k0 + g * 8;
      f32x4 a = *(const f32x4*)src;
      f32x4 b = *(const f32x4*)(src + 4);
      if (MODE == 1) {
        const float* s2 = B1 + (size_t)row * K + k0 + g * 8;
        a = a + *(const f32x4*)s2;
        b = b + *(const f32x4*)(s2 + 4);
      }
      *(short8*)(Bs + row * 64 + (g ^ (row & 7)) * 8) = pack8(a, b);
    }
    __syncthreads();
    mfma_phase(As, Bs, acc);
    __syncthreads();
  }
}

__global__ __launch_bounds__(256) void k_bw_fb(Params P, float* __restrict__ out)
{
  __shared__ u16 As[128 * 64];
  __shared__ u16 Bs[128 * 64];
  int b   = blockIdx.x;
  int mat = b >> 4, loc = b & 15;
  int bmw = loc >> 2, bnw = loc & 3;

  f32x4 acc[4][4];
  zero_acc(acc);
  int obase;
  if (mat == 0) {
    nn_term_fb(P.Eg0 + (size_t)bmw * 128 * 1024, P.W0 + bnw * 128, 1024, As, Bs, acc);
    nn_term_fb(P.Ed1 + (size_t)bmw * 128 * 512,  P.V1 + bnw * 128,  512, As, Bs, acc);
    obase = 0;
  } else {
    nn_term_fb(P.Eg1 + (size_t)bmw * 128 * 512,  P.W1 + bnw * 128,  512, As, Bs, acc);
    nn_term_fb(P.Ed2 + (size_t)bmw * 128 * 256,  P.V2 + bnw * 128,  256, As, Bs, acc);
    obase = 2048;
  }
  const int lane = threadIdx.x & 63;
  const int w    = threadIdx.x >> 6;
  const int l16  = lane & 15, lq = lane >> 4;
  const int wm   = (w >> 1) * 64, wn = (w & 1) * 64;
#pragma unroll
  for (int rt = 0; rt < 4; rt++)
#pragma unroll
    for (int ct = 0; ct < 4; ct++)
#pragma unroll
      for (int i = 0; i < 4; i++) {
        int rl = wm + rt * 16 + lq * 4 + i;
        int cl = wn + ct * 16 + l16;
        out[(size_t)rl * 4096 + obase + bmw * 128 + bnw * 512 + cl] = -acc[rt][ct][i];
      }
}

__global__ __launch_bounds__(256) void k_main_fb(Params P, float* __restrict__ out, int fix)
{
  __shared__ u16 As[128 * 64];
  __shared__ u16 Bs[128 * 64];
  int job, bm, bn;
  if (fix) {
    job = blockIdx.x >> 2; bn = blockIdx.x & 3; bm = 0;
  } else {
    job = blockIdx.x >> 8;
    int local = blockIdx.x & 255;
    bm = local & 63; bn = local >> 6;
    if (bm == 0) return;
  }

  f32x4 acc[4][4];
  zero_acc(acc);
  const float *jin, *vin, *xin;
  int obase;
  size_t am = (size_t)bm * 128;

  if (job == 0) {
    gemm_term_fb<0>(P.s2      + am * 512,  P.W1  + (size_t)bn * 128 * 512,  nullptr, 512,  As, Bs, acc);
    gemm_term_fb<1>(P.x_input + am * 1024, P.V0  + (size_t)bn * 128 * 1024,
                    P.Eg0 + (size_t)bn * 128 * 1024, 1024, As, Bs, acc);
    gemm_term_fb<0>(P.x2      + am * 512,  P.Ed1 + (size_t)bn * 128 * 512,  nullptr, 512,  As, Bs, acc);
    gemm_term_fb<2>(P.s1      + am * 512,  out + 0 + bn * 128,              nullptr, 512,  As, Bs, acc);
    jin = P.j1; vin = P.v1; xin = P.x1; obase = 0;
  } else {
    gemm_term_fb<1>(P.y_target + am * 256, P.W2  + (size_t)bn * 128 * 256,
                    P.Ed2 + (size_t)bn * 128 * 256, 256, As, Bs, acc);
    gemm_term_fb<0>(P.s1      + am * 512,  P.V1  + (size_t)bn * 128 * 512,  nullptr, 512,  As, Bs, acc);
    gemm_term_fb<0>(P.x1      + am * 512,  P.Eg1 + (size_t)bn * 128 * 512,  nullptr, 512,  As, Bs, acc);
    gemm_term_fb<2>(P.s2      + am * 512,  out + 2048 + bn * 128,           nullptr, 512,  As, Bs, acc);
    jin = P.j2; vin = P.v2; xin = P.x2; obase = 2048;
  }

  const int lane = threadIdx.x & 63;
  const int w    = threadIdx.x >> 6;
  const int l16  = lane & 15, lq = lane >> 4;
  const int wm   = (w >> 1) * 64, wn = (w & 1) * 64;

#pragma unroll
  for (int rt = 0; rt < 4; rt++)
#pragma unroll
    for (int ct = 0; ct < 4; ct++)
#pragma unroll
      for (int i = 0; i < 4; i++) {
        int row    = bm * 128 + wm + rt * 16 + lq * 4 + i;
        int col    = bn * 128 + wn + ct * 16 + l16;
        size_t idx = (size_t)row * 512 + col;
        float xf = xin[idx];
        float total = acc[rt][ct][i] - 2.0f * xf;
        float jf = jin[idx];
        float vf = vin[idx];
        jf = jf + 0.1f * (-0.25f * jf + total);
        vf = vf + 0.05f * (-vf + jf);
        float sf = (vf > 0.4f) ? 1.0f : 0.0f;
        vf = vf * (1.0f - sf);
        xf = xf + (-xf / 20.0f + sf);
        size_t ob = (size_t)row * 4096 + obase + col;
        out[ob]        = jf;
        out[ob + 512]  = vf;
        out[ob + 1024] = xf;
        out[ob + 1536] = sf;
      }
}

// ---------------------------------------------------------------------------
extern "C" void kernel_launch(void* const* d_in, const int* in_sizes, int n_in,
                              void* d_out, int out_size, void* d_ws, size_t ws_size,
                              hipStream_t stream)
{
  Params P;
  P.x_input  = (const float*)d_in[0];
  P.y_target = (const float*)d_in[1];
  P.j1 = (const float*)d_in[2];
  P.v1 = (const float*)d_in[3];
  P.s1 = (const float*)d_in[4];
  P.x1 = (const float*)d_in[5];
  P.j2 = (const float*)d_in[6];
  P.v2 = (const float*)d_in[7];
  P.s2 = (const float*)d_in[8];
  P.x2 = (const float*)d_in[9];
  P.W0 = (const float*)d_in[10];
  P.W1 = (const float*)d_in[11];
  P.W2 = (const float*)d_in[12];
  P.V0 = (const float*)d_in[13];
  P.V1 = (const float*)d_in[14];
  P.V2 = (const float*)d_in[15];
  P.Eg0 = (const float*)d_in[16];
  P.Eg1 = (const float*)d_in[17];
  P.Ed1 = (const float*)d_in[20];
  P.Ed2 = (const float*)d_in[21];
  (void)in_sizes; (void)n_in; (void)out_size;

  float* out = (float*)d_out;

  if (ws_size >= 62652416) {
    char* ws = (char*)d_ws;
    u16* xin_b = (u16*)(ws + 0);         // [8192,1024]
    u16* y_b   = (u16*)(ws + 16777216);  // [8192,256]
    u16* s1_b  = (u16*)(ws + 20971520);  // [8192,512]
    u16* x1_b  = (u16*)(ws + 29360128);
    u16* s2_b  = (u16*)(ws + 37748736);
    u16* x2_b  = (u16*)(ws + 46137344);
    u16* W1_b  = (u16*)(ws + 54525952);  // [512,512]
    u16* P1_b  = (u16*)(ws + 55050240);  // [512,1024] = V0+Eg0
    u16* Ed1_b = (u16*)(ws + 56098816);  // [512,512]
    u16* V1_b  = (u16*)(ws + 56623104);
    u16* Eg1_b = (u16*)(ws + 57147392);
    u16* P2_b  = (u16*)(ws + 57671680);  // [512,256] = W2+Ed2
    u16* Bw1_b = (u16*)(ws + 57933824);  // [512,512]
    u16* Bw2_b = (u16*)(ws + 58458112);  // [512,512]
    u16* W0t_b = (u16*)(ws + 58982400);  // [512,1024]
    u16* V1t_b = (u16*)(ws + 60030976);  // [512,512]
    u16* W1t_b = (u16*)(ws + 60555264);  // [512,512]
    u16* V2t_b = (u16*)(ws + 61079552);  // [512,256]
    u16* Eg0_b = (u16*)(ws + 61341696);  // [512,1024]
    u16* Ed2_b = (u16*)(ws + 62390272);  // [512,256]  (end 62652416)

    PrepArgs pa;
    pa.jb[0]  = { P.x_input,  nullptr, xin_b,     0 };
    pa.jb[1]  = { P.y_target, nullptr, y_b,    4096 };
    pa.jb[2]  = { P.s1,       nullptr, s1_b,   5120 };
    pa.jb[3]  = { P.x1,       nullptr, x1_b,   7168 };
    pa.jb[4]  = { P.s2,       nullptr, s2_b,   9216 };
    pa.jb[5]  = { P.x2,       nullptr, x2_b,  11264 };
    pa.jb[6]  = { P.W1,       nullptr, W1_b,  13312 };
    pa.jb[7]  = { P.V0,       P.Eg0,   P1_b,  13440 };
    pa.jb[8]  = { P.Ed1,      nullptr, Ed1_b, 13696 };
    pa.jb[9]  = { P.V1,       nullptr, V1_b,  13824 };
    pa.jb[10] = { P.Eg1,      nullptr, Eg1_b, 13952 };
    pa.jb[11] = { P.W2,       P.Ed2,   P2_b,  14080 };
    pa.jb[12] = { P.Eg0,      nullptr, Eg0_b, 14144 };
    pa.jb[13] = { P.Ed2,      nullptr, Ed2_b, 14400 };   // 64 blocks -> 14464
    pa.tj[0]  = { P.W0, W0t_b, 1024,    0 };   // 512 tiles
    pa.tj[1]  = { P.V1, V1t_b,  512,  512 };   // 256
    pa.tj[2]  = { P.W1, W1t_b,  512,  768 };   // 256
    pa.tj[3]  = { P.V2, V2t_b,  256, 1024 };   // 128 -> 1152
    k_prep<<<dim3(15616), dim3(256), 0, stream>>>(pa);

    BW2Args ba;
    ba.Eg0b = Eg0_b; ba.W0tb = W0t_b; ba.Ed1b = Ed1_b; ba.V1tb = V1t_b;
    ba.Eg1b = Eg1_b; ba.W1tb = W1t_b; ba.Ed2b = Ed2_b; ba.V2tb = V2t_b;
    ba.Bw1b = Bw1_b; ba.Bw2b = Bw2_b;
    k_bw2<<<dim3(128), dim3(256), 0, stream>>>(ba);

    MArgsF ma;
    ma.j[0].A[0] = s2_b;  ma.j[0].B[0] = W1_b;  ma.j[0].K[0] = 512;
    ma.j[0].A[1] = xin_b; ma.j[0].B[1] = P1_b;  ma.j[0].K[1] = 1024;
    ma.j[0].A[2] = x2_b;  ma.j[0].B[2] = Ed1_b; ma.j[0].K[2] = 512;
    ma.j[0].A[3] = s1_b;  ma.j[0].B[3] = Bw1_b; ma.j[0].K[3] = 512;
    ma.j[0].jin = P.j1; ma.j[0].vin = P.v1; ma.j[0].xin = P.x1; ma.j[0].obase = 0;
    ma.j[1].A[0] = y_b;   ma.j[1].B[0] = P2_b;  ma.j[1].K[0] = 256;
    ma.j[1].A[1] = s1_b;  ma.j[1].B[1] = V1_b;  ma.j[1].K[1] = 512;
    ma.j[1].A[2] = x1_b;  ma.j[1].B[2] = Eg1_b; ma.j[1].K[2] = 512;
    ma.j[1].A[3] = s2_b;  ma.j[1].B[3] = Bw2_b; ma.j[1].K[3] = 512;
    ma.j[1].jin = P.j2; ma.j[1].vin = P.v2; ma.j[1].xin = P.x2; ma.j[1].obase = 2048;
    k_main_fast<<<dim3(1024), dim3(256), 0, stream>>>(ma, out);
  } else {
    k_bw_fb<<<dim3(32), dim3(256), 0, stream>>>(P, out);
    k_main_fb<<<dim3(512), dim3(256), 0, stream>>>(P, out, 0);
    k_main_fb<<<dim3(8), dim3(256), 0, stream>>>(P, out, 1);
  }
}

// Round 9
// 387.626 us; speedup vs baseline: 1.3879x; 1.0809x over previous
//
#include <hip/hip_runtime.h>
#include <stdint.h>
#include <stddef.h>

typedef unsigned short u16;
typedef __attribute__((ext_vector_type(8))) short short8;
typedef __attribute__((ext_vector_type(4))) float f32x4;

#define DEVI __device__ __forceinline__

DEVI u16 f2bf(float f) {
  union { float f; unsigned u; } c; c.f = f;
  unsigned r = c.u + 0x7fff + ((c.u >> 16) & 1);
  return (u16)(r >> 16);
}

DEVI short8 pack8(f32x4 a, f32x4 b) {
  short8 v;
#pragma unroll
  for (int i = 0; i < 4; i++) { v[i] = (short)f2bf(a[i]); v[i + 4] = (short)f2bf(b[i]); }
  return v;
}

typedef __attribute__((address_space(1))) const void global_cvoid;
typedef __attribute__((address_space(3))) void lds_void;

// ---------------------------------------------------------------------------
// LDS layout per tile: row*64 bf16; 16B granule slot g of row r holds global
// granule g^(r&7) -> fragment ds_read_b128 aliases 2-way (free).
// Measured: SQ_LDS_BANK_CONFLICT == 0 with this scheme.
//
// Structure verdicts (measured, this problem):
//   main 64x128 LDS 2-barrier 4/CU + stagger : 107 us  <- LOCKED (best)
//   128x128 2/CU: 117 | 64x64 8/CU: 131 | pipelined (any form): 139-142
//   direct-global barrier-free: 258
// DEPENDENCY RULE (r8 failure): bw2 blocks inside k_merged require ALL of
// {W0t,V1t,W1t,V2t,Eg0,Ed2,Ed1,Eg1} bf16 produced by k_prep_a (prior
// dispatch). Intra-kernel block families have NO ordering guarantee.
// ---------------------------------------------------------------------------

// 128x128 4-wave phase (fallback): acc[4][4], waves 2x2 of 64x64
DEVI void mfma_phase(const u16* As, const u16* Bs, f32x4 acc[4][4])
{
  const int lane = threadIdx.x & 63;
  const int w    = threadIdx.x >> 6;
  const int l16  = lane & 15, lq = lane >> 4;
  const int wm   = (w >> 1) * 64, wn = (w & 1) * 64;
#pragma unroll
  for (int kc = 0; kc < 2; kc++) {
    short8 afr[4], bfr[4];
#pragma unroll
    for (int rt = 0; rt < 4; rt++) {
      int m  = wm + rt * 16 + l16;
      int gr = (kc * 4 + lq) ^ (m & 7);
      afr[rt] = *(const short8*)(As + m * 64 + gr * 8);
    }
#pragma unroll
    for (int ct = 0; ct < 4; ct++) {
      int n  = wn + ct * 16 + l16;
      int gr = (kc * 4 + lq) ^ (n & 7);
      bfr[ct] = *(const short8*)(Bs + n * 64 + gr * 8);
    }
#pragma unroll
    for (int rt = 0; rt < 4; rt++)
#pragma unroll
      for (int ct = 0; ct < 4; ct++)
        acc[rt][ct] = __builtin_amdgcn_mfma_f32_16x16x32_bf16(afr[rt], bfr[ct], acc[rt][ct], 0, 0, 0);
  }
}

// 64x64 4-wave phase (bw2): acc[2][2], waves 2x2 of 32x32
DEVI void mfma_phase32(const u16* As, const u16* Bs, f32x4 acc[2][2])
{
  const int lane = threadIdx.x & 63;
  const int w    = threadIdx.x >> 6;
  const int l16  = lane & 15, lq = lane >> 4;
  const int wm   = (w >> 1) * 32, wn = (w & 1) * 32;
#pragma unroll
  for (int kc = 0; kc < 2; kc++) {
    short8 afr[2], bfr[2];
#pragma unroll
    for (int rt = 0; rt < 2; rt++) {
      int m  = wm + rt * 16 + l16;
      int gr = (kc * 4 + lq) ^ (m & 7);
      afr[rt] = *(const short8*)(As + m * 64 + gr * 8);
    }
#pragma unroll
    for (int ct = 0; ct < 2; ct++) {
      int n  = wn + ct * 16 + l16;
      int gr = (kc * 4 + lq) ^ (n & 7);
      bfr[ct] = *(const short8*)(Bs + n * 64 + gr * 8);
    }
#pragma unroll
    for (int rt = 0; rt < 2; rt++)
#pragma unroll
      for (int ct = 0; ct < 2; ct++)
        acc[rt][ct] = __builtin_amdgcn_mfma_f32_16x16x32_bf16(afr[rt], bfr[ct], acc[rt][ct], 0, 0, 0);
  }
}

// 64x128 4-wave phase (main): acc[2][4], waves 2x2 of 32x64
DEVI void mfma_phase64(const u16* As, const u16* Bs, f32x4 acc[2][4])
{
  const int lane = threadIdx.x & 63;
  const int w    = threadIdx.x >> 6;
  const int l16  = lane & 15, lq = lane >> 4;
  const int wm   = (w >> 1) * 32, wn = (w & 1) * 64;
#pragma unroll
  for (int kc = 0; kc < 2; kc++) {
    short8 afr[2], bfr[4];
#pragma unroll
    for (int rt = 0; rt < 2; rt++) {
      int m  = wm + rt * 16 + l16;
      int gr = (kc * 4 + lq) ^ (m & 7);
      afr[rt] = *(const short8*)(As + m * 64 + gr * 8);
    }
#pragma unroll
    for (int ct = 0; ct < 4; ct++) {
      int n  = wn + ct * 16 + l16;
      int gr = (kc * 4 + lq) ^ (n & 7);
      bfr[ct] = *(const short8*)(Bs + n * 64 + gr * 8);
    }
#pragma unroll
    for (int rt = 0; rt < 2; rt++)
#pragma unroll
      for (int ct = 0; ct < 4; ct++)
        acc[rt][ct] = __builtin_amdgcn_mfma_f32_16x16x32_bf16(afr[rt], bfr[ct], acc[rt][ct], 0, 0, 0);
  }
}

DEVI void zero_acc(f32x4 acc[4][4]) {
  f32x4 z = {0.f, 0.f, 0.f, 0.f};
#pragma unroll
  for (int a = 0; a < 4; a++)
#pragma unroll
    for (int b = 0; b < 4; b++) acc[a][b] = z;
}

DEVI void zero_acc22(f32x4 acc[2][2]) {
  f32x4 z = {0.f, 0.f, 0.f, 0.f};
#pragma unroll
  for (int a = 0; a < 2; a++)
#pragma unroll
    for (int b = 0; b < 2; b++) acc[a][b] = z;
}

DEVI void zero_acc24(f32x4 acc[2][4]) {
  f32x4 z = {0.f, 0.f, 0.f, 0.f};
#pragma unroll
  for (int a = 0; a < 2; a++)
#pragma unroll
    for (int b = 0; b < 4; b++) acc[a][b] = z;
}

struct Params {
  const float *x_input, *y_target, *j1, *v1, *s1, *x1, *j2, *v2, *s2, *x2;
  const float *W0, *W1, *W2, *V0, *V1, *V2, *Eg0, *Eg1, *Ed1, *Ed2;
};

// ===========================================================================
// FAST PATH
// ===========================================================================

// async-DMA stage of one (RR*32)x64 bf16 tile; swizzle applied on the GLOBAL
// fetch address (LDS dest of global_load_lds is fixed: base + lane*16B).
template <int RR>
DEVI void stage_async(const u16* gbase, int ldr, int k0, u16* lds)
{
  const int t = threadIdx.x;
  const int lane = t & 63, w = t >> 6;
#pragma unroll
  for (int tt = 0; tt < RR; tt++) {
    int rowbase = w * (RR * 8) + tt * 8;
    int row = rowbase + (lane >> 3);
    int gsw = (lane & 7) ^ (row & 7);
    __builtin_amdgcn_global_load_lds(
        (global_cvoid*)(gbase + (size_t)row * ldr + k0 + gsw * 8),
        (lds_void*)(lds + rowbase * 64), 16, 0, 0);
  }
}

// simple 2-barrier 64x64 term (bw2)
DEVI void gemm_term64(const u16* A, const u16* B, int K,
                      u16* As, u16* Bs, f32x4 acc[2][2])
{
  for (int k0 = 0; k0 < K; k0 += 64) {
    stage_async<2>(A, K, k0, As);
    stage_async<2>(B, K, k0, Bs);
    __syncthreads();
    mfma_phase32(As, Bs, acc);
    __syncthreads();
  }
}

// simple 2-barrier 64x128 term (k_main) — LOCKED structure (107 us).
DEVI void gemm_term_main(const u16* A, const u16* B, int K,
                         u16* As, u16* Bs, f32x4 acc[2][4])
{
  for (int k0 = 0; k0 < K; k0 += 64) {
    stage_async<2>(A, K, k0, As);
    stage_async<4>(B, K, k0, Bs);
    __syncthreads();
    mfma_phase64(As, Bs, acc);
    __syncthreads();
  }
}

// convert helper: one 2048-elem chunk (256 threads x 8)
struct PJob { const float *s0, *s1; u16* dst; int start; };

DEVI void do_convert_chunk(const PJob& pj, int c, int t)
{
  size_t e0 = ((size_t)(c - pj.start) * 256 + t) * 8;
  const float* s0 = pj.s0 + e0;
  f32x4 a  = *(const f32x4*)s0;
  f32x4 b4 = *(const f32x4*)(s0 + 4);
  if (pj.s1) {
    const float* s1 = pj.s1 + e0;
    a  = a  + *(const f32x4*)s1;
    b4 = b4 + *(const f32x4*)(s1 + 4);
  }
  *(short8*)(pj.dst + e0) = pack8(a, b4);
}

// ---------------------------------------------------------------------------
// k_prep_a: ALL bw2 inputs.
//   blocks [0,1152):    32x32 transpose tiles W0/V1/W1/V2 -> bf16 [512,J]
//   blocks [1152,1728): Eg0/Ed2/Ed1/Eg1 fp32->bf16 converts (2048 elem/blk)
// ---------------------------------------------------------------------------
struct TJob { const float* in; u16* out; int J, tbase; };
struct PrepAArgs { TJob tj[4]; PJob jb[4]; };

__global__ __launch_bounds__(256) void k_prep_a(PrepAArgs A)
{
  __shared__ u16 T[32][33];
  int b = blockIdx.x;
  int t = threadIdx.x;
  if (b >= 1152) {
    int ji = 0;
#pragma unroll
    for (int i = 1; i < 4; i++)
      if (b >= A.jb[i].start) ji = i;
    do_convert_chunk(A.jb[ji], b, t);
    return;
  }
  int ji = 0;
#pragma unroll
  for (int i = 1; i < 4; i++)
    if (b >= A.tj[i].tbase) ji = i;
  TJob jb = A.tj[ji];
  int local = b - jb.tbase;
  int tm = local >> 4;          // J/32 tile rows
  int tk = local & 15;          // 512/32 tile cols
  int tx = t & 31, ty = t >> 5; // ty 0..7
#pragma unroll
  for (int i = 0; i < 4; i++) {
    int r = ty + i * 8;
    T[r][tx] = f2bf(jb.in[(size_t)(tm * 32 + r) * 512 + tk * 32 + tx]);
  }
  __syncthreads();
#pragma unroll
  for (int i = 0; i < 4; i++) {
    int r = ty + i * 8;
    jb.out[(size_t)(tk * 32 + r) * jb.J + tm * 32 + tx] = T[tx][r];
  }
}

// ---------------------------------------------------------------------------
// k_merged: blocks [0,128):  bw2 FAST (64x64 tiles, DMA path; ALL inputs from
//                            k_prep_a): Bw1=-(Eg0@W0+Ed1@V1), Bw2=-(Eg1@W1+Ed2@V2)
//           blocks [128,..): remaining fp32->bf16 converts, 4x2048 elem/blk.
// bw2 blocks dispatched first; they hide under the BW-bound convert stream.
// ---------------------------------------------------------------------------
struct MergedArgs {
  const u16 *Eg0b, *W0tb, *Ed1b, *V1tb, *Eg1b, *W1tb, *Ed2b, *V2tb;
  u16 *Bw1b, *Bw2b;
  PJob jb[10];
};

__global__ __launch_bounds__(256) void k_merged(MergedArgs A)
{
  __shared__ u16 As[64 * 64];
  __shared__ u16 Bs[64 * 64];
  int b = blockIdx.x;
  int t = threadIdx.x;

  if (b < 128) {
    int mat = b >> 6, loc = b & 63;
    int bmw = loc >> 3, bnw = loc & 7;
    f32x4 acc[2][2];
    zero_acc22(acc);
    u16* dst;
    if (mat == 0) {
      gemm_term64(A.Eg0b + (size_t)bmw * 64 * 1024, A.W0tb + (size_t)bnw * 64 * 1024, 1024, As, Bs, acc);
      gemm_term64(A.Ed1b + (size_t)bmw * 64 * 512,  A.V1tb + (size_t)bnw * 64 * 512,   512, As, Bs, acc);
      dst = A.Bw1b;
    } else {
      gemm_term64(A.Eg1b + (size_t)bmw * 64 * 512,  A.W1tb + (size_t)bnw * 64 * 512,   512, As, Bs, acc);
      gemm_term64(A.Ed2b + (size_t)bmw * 64 * 256,  A.V2tb + (size_t)bnw * 64 * 256,   256, As, Bs, acc);
      dst = A.Bw2b;
    }
    const int lane = t & 63;
    const int w    = t >> 6;
    const int l16  = lane & 15, lq = lane >> 4;
    const int wm   = (w >> 1) * 32, wn = (w & 1) * 32;
#pragma unroll
    for (int rt = 0; rt < 2; rt++)
#pragma unroll
      for (int ct = 0; ct < 2; ct++)
#pragma unroll
        for (int i = 0; i < 4; i++) {
          int rl = wm + rt * 16 + lq * 4 + i;
          int cl = wn + ct * 16 + l16;
          dst[(size_t)(bmw * 64 + rl) * 512 + bnw * 64 + cl] = f2bf(-acc[rt][ct][i]);
        }
    return;
  }

  // convert blocks: 4 chunks of 2048 elements each
  int cb = (b - 128) * 4;
  for (int it = 0; it < 4; it++) {
    int c = cb + it;
    int ji = 0;
#pragma unroll
    for (int i = 1; i < 10; i++)
      if (c >= A.jb[i].start) ji = i;
    do_convert_chunk(A.jb[ji], c, t);
  }
}

// ---------------------------------------------------------------------------
// k_main_fast: r4 VERBATIM (locked). 64x128 output tiles, 1024 blocks,
// 4 blocks/CU, simple 2-barrier loop, entry stagger, fused LIF epilogue.
// ---------------------------------------------------------------------------
struct MJobF {
  const u16* A[4]; const u16* B[4]; int K[4];
  const float *jin, *vin, *xin;
  int obase;
};
struct MArgsF { MJobF j[2]; };

__global__ __launch_bounds__(256, 4) void k_main_fast(MArgsF P, float* __restrict__ out)
{
  __shared__ u16 As[64 * 64];
  __shared__ u16 Bs[128 * 64];
  int bid   = blockIdx.x;
  int job   = bid >> 9;
  int local = bid & 511;
  int bm = local & 127, bn = local >> 7;
  MJobF jb = P.j[job];

  // de-convoy: offset co-resident blocks by ~0/0.5/1/1.5k cycles.
  switch (((bid >> 8) ^ bid) & 3) {
    case 1: __builtin_amdgcn_s_sleep(8); break;
    case 2: __builtin_amdgcn_s_sleep(8); __builtin_amdgcn_s_sleep(8); break;
    case 3: __builtin_amdgcn_s_sleep(8); __builtin_amdgcn_s_sleep(8);
            __builtin_amdgcn_s_sleep(8); break;
    default: break;
  }

  f32x4 acc[2][4];
  zero_acc24(acc);
#pragma unroll
  for (int p = 0; p < 4; p++)
    gemm_term_main(jb.A[p] + (size_t)bm * 64 * jb.K[p],
                   jb.B[p] + (size_t)bn * 128 * jb.K[p], jb.K[p], As, Bs, acc);

  const int lane = threadIdx.x & 63;
  const int w    = threadIdx.x >> 6;
  const int l16  = lane & 15, lq = lane >> 4;
  const int wm   = (w >> 1) * 32, wn = (w & 1) * 64;

#pragma unroll
  for (int rt = 0; rt < 2; rt++)
#pragma unroll
    for (int ct = 0; ct < 4; ct++)
#pragma unroll
      for (int i = 0; i < 4; i++) {
        int row    = bm * 64 + wm + rt * 16 + lq * 4 + i;
        int col    = bn * 128 + wn + ct * 16 + l16;
        size_t idx = (size_t)row * 512 + col;
        float xf = jb.xin[idx];
        float total = acc[rt][ct][i] - 2.0f * xf;
        float jf = jb.jin[idx];
        float vf = jb.vin[idx];
        jf = jf + 0.1f * (-0.25f * jf + total);
        vf = vf + 0.05f * (-vf + jf);
        float sf = (vf > 0.4f) ? 1.0f : 0.0f;
        vf = vf * (1.0f - sf);
        xf = xf + (-xf / 20.0f + sf);
        size_t ob = (size_t)row * 4096 + jb.obase + col;
        out[ob]        = jf;
        out[ob + 512]  = vf;
        out[ob + 1024] = xf;
        out[ob + 1536] = sf;
      }
}

// ===========================================================================
// FALLBACK PATH (verbatim; used only if ws too small)
// ===========================================================================

DEVI void stage_A_fb(const float* A, int ldr, int k0, u16* dst)
{
  const int t = threadIdx.x;
  const int g = t & 7, rb = t >> 3;
#pragma unroll
  for (int p = 0; p < 4; p++) {
    int row = p * 32 + rb;
    const float* src = A + (size_t)row * ldr + k0 + g * 8;
    f32x4 a = *(const f32x4*)src;
    f32x4 b = *(const f32x4*)(src + 4);
    *(short8*)(dst + row * 64 + (g ^ (row & 7)) * 8) = pack8(a, b);
  }
}

DEVI void nn_term_fb(const float* A, const float* B, int K, u16* As, u16* Bs, f32x4 acc[4][4])
{
  const int t  = threadIdx.x;
  const int ks = t >> 4, ng = t & 15;
  for (int k0 = 0; k0 < K; k0 += 64) {
    stage_A_fb(A, K, k0, As);
#pragma unroll
    for (int i = 0; i < 4; i++) {
      int kloc = i * 16 + ks;
      const float* src = B + (size_t)(k0 + kloc) * 512 + ng * 8;
      f32x4 a = *(const f32x4*)src;
      f32x4 b = *(const f32x4*)(src + 4);
#pragma unroll
      for (int e = 0; e < 8; e++) {
        int nloc = ng * 8 + e;
        float val = (e < 4) ? a[e] : b[e - 4];
        Bs[nloc * 64 + ((kloc >> 3) ^ (nloc & 7)) * 8 + (kloc & 7)] = f2bf(val);
      }
    }
    __syncthreads();
    mfma_phase(As, Bs, acc);
    __syncthreads();
  }
}

template <int MODE>
DEVI void gemm_term_fb(const float* A, const float* B0, const float* B1, int K,
                       u16* As, u16* Bs, f32x4 acc[4][4])
{
  const int t = threadIdx.x;
  const int g = t & 7, rb = t >> 3;
  for (int k0 = 0; k0 < K; k0 += 64) {
    stage_A_fb(A, K, k0, As);
#pragma unroll
    for (int p = 0; p < 4; p++) {
      int row = p * 32 + rb;
      const float* src;
      if (MODE == 2) src = B0 + (size_t)row * 4096 + (k0 >> 7) * 512 + (k0 & 127) + g * 8;
      else           src = B0 + (size_t)row * K + k0 + g * 8;
      f32x4 a = *(const f32x4*)src;
      f32x4 b = *(const f32x4*)(src + 4);
      if (MODE == 1) {
        const float* s2 = B1 + (size_t)row * K + k0 + g * 8;
        a = a + *(const f32x4*)s2;
        b = b + *(const f32x4*)(s2 + 4);
      }
      *(short8*)(Bs + row * 64 + (g ^ (row & 7)) * 8) = pack8(a, b);
    }
    __syncthreads();
    mfma_phase(As, Bs, acc);
    __syncthreads();
  }
}

__global__ __launch_bounds__(256) void k_bw_fb(Params P, float* __restrict__ out)
{
  __shared__ u16 As[128 * 64];
  __shared__ u16 Bs[128 * 64];
  int b   = blockIdx.x;
  int mat = b >> 4, loc = b & 15;
  int bmw = loc >> 2, bnw = loc & 3;

  f32x4 acc[4][4];
  zero_acc(acc);
  int obase;
  if (mat == 0) {
    nn_term_fb(P.Eg0 + (size_t)bmw * 128 * 1024, P.W0 + bnw * 128, 1024, As, Bs, acc);
    nn_term_fb(P.Ed1 + (size_t)bmw * 128 * 512,  P.V1 + bnw * 128,  512, As, Bs, acc);
    obase = 0;
  } else {
    nn_term_fb(P.Eg1 + (size_t)bmw * 128 * 512,  P.W1 + bnw * 128,  512, As, Bs, acc);
    nn_term_fb(P.Ed2 + (size_t)bmw * 128 * 256,  P.V2 + bnw * 128,  256, As, Bs, acc);
    obase = 2048;
  }
  const int lane = threadIdx.x & 63;
  const int w    = threadIdx.x >> 6;
  const int l16  = lane & 15, lq = lane >> 4;
  const int wm   = (w >> 1) * 64, wn = (w & 1) * 64;
#pragma unroll
  for (int rt = 0; rt < 4; rt++)
#pragma unroll
    for (int ct = 0; ct < 4; ct++)
#pragma unroll
      for (int i = 0; i < 4; i++) {
        int rl = wm + rt * 16 + lq * 4 + i;
        int cl = wn + ct * 16 + l16;
        out[(size_t)rl * 4096 + obase + bmw * 128 + bnw * 512 + cl] = -acc[rt][ct][i];
      }
}

__global__ __launch_bounds__(256) void k_main_fb(Params P, float* __restrict__ out, int fix)
{
  __shared__ u16 As[128 * 64];
  __shared__ u16 Bs[128 * 64];
  int job, bm, bn;
  if (fix) {
    job = blockIdx.x >> 2; bn = blockIdx.x & 3; bm = 0;
  } else {
    job = blockIdx.x >> 8;
    int local = blockIdx.x & 255;
    bm = local & 63; bn = local >> 6;
    if (bm == 0) return;
  }

  f32x4 acc[4][4];
  zero_acc(acc);
  const float *jin, *vin, *xin;
  int obase;
  size_t am = (size_t)bm * 128;

  if (job == 0) {
    gemm_term_fb<0>(P.s2      + am * 512,  P.W1  + (size_t)bn * 128 * 512,  nullptr, 512,  As, Bs, acc);
    gemm_term_fb<1>(P.x_input + am * 1024, P.V0  + (size_t)bn * 128 * 1024,
                    P.Eg0 + (size_t)bn * 128 * 1024, 1024, As, Bs, acc);
    gemm_term_fb<0>(P.x2      + am * 512,  P.Ed1 + (size_t)bn * 128 * 512,  nullptr, 512,  As, Bs, acc);
    gemm_term_fb<2>(P.s1      + am * 512,  out + 0 + bn * 128,              nullptr, 512,  As, Bs, acc);
    jin = P.j1; vin = P.v1; xin = P.x1; obase = 0;
  } else {
    gemm_term_fb<1>(P.y_target + am * 256, P.W2  + (size_t)bn * 128 * 256,
                    P.Ed2 + (size_t)bn * 128 * 256, 256, As, Bs, acc);
    gemm_term_fb<0>(P.s1      + am * 512,  P.V1  + (size_t)bn * 128 * 512,  nullptr, 512,  As, Bs, acc);
    gemm_term_fb<0>(P.x1      + am * 512,  P.Eg1 + (size_t)bn * 128 * 512,  nullptr, 512,  As, Bs, acc);
    gemm_term_fb<2>(P.s2      + am * 512,  out + 2048 + bn * 128,           nullptr, 512,  As, Bs, acc);
    jin = P.j2; vin = P.v2; xin = P.x2; obase = 2048;
  }

  const int lane = threadIdx.x & 63;
  const int w    = threadIdx.x >> 6;
  const int l16  = lane & 15, lq = lane >> 4;
  const int wm   = (w >> 1) * 64, wn = (w & 1) * 64;

#pragma unroll
  for (int rt = 0; rt < 4; rt++)
#pragma unroll
    for (int ct = 0; ct < 4; ct++)
#pragma unroll
      for (int i = 0; i < 4; i++) {
        int row    = bm * 128 + wm + rt * 16 + lq * 4 + i;
        int col    = bn * 128 + wn + ct * 16 + l16;
        size_t idx = (size_t)row * 512 + col;
        float xf = xin[idx];
        float total = acc[rt][ct][i] - 2.0f * xf;
        float jf = jin[idx];
        float vf = vin[idx];
        jf = jf + 0.1f * (-0.25f * jf + total);
        vf = vf + 0.05f * (-vf + jf);
        float sf = (vf > 0.4f) ? 1.0f : 0.0f;
        vf = vf * (1.0f - sf);
        xf = xf + (-xf / 20.0f + sf);
        size_t ob = (size_t)row * 4096 + obase + col;
        out[ob]        = jf;
        out[ob + 512]  = vf;
        out[ob + 1024] = xf;
        out[ob + 1536] = sf;
      }
}

// ---------------------------------------------------------------------------
extern "C" void kernel_launch(void* const* d_in, const int* in_sizes, int n_in,
                              void* d_out, int out_size, void* d_ws, size_t ws_size,
                              hipStream_t stream)
{
  Params P;
  P.x_input  = (const float*)d_in[0];
  P.y_target = (const float*)d_in[1];
  P.j1 = (const float*)d_in[2];
  P.v1 = (const float*)d_in[3];
  P.s1 = (const float*)d_in[4];
  P.x1 = (const float*)d_in[5];
  P.j2 = (const float*)d_in[6];
  P.v2 = (const float*)d_in[7];
  P.s2 = (const float*)d_in[8];
  P.x2 = (const float*)d_in[9];
  P.W0 = (const float*)d_in[10];
  P.W1 = (const float*)d_in[11];
  P.W2 = (const float*)d_in[12];
  P.V0 = (const float*)d_in[13];
  P.V1 = (const float*)d_in[14];
  P.V2 = (const float*)d_in[15];
  P.Eg0 = (const float*)d_in[16];
  P.Eg1 = (const float*)d_in[17];
  P.Ed1 = (const float*)d_in[20];
  P.Ed2 = (const float*)d_in[21];
  (void)in_sizes; (void)n_in; (void)out_size;

  float* out = (float*)d_out;

  if (ws_size >= 62652416) {
    char* ws = (char*)d_ws;
    u16* xin_b = (u16*)(ws + 0);         // [8192,1024]
    u16* y_b   = (u16*)(ws + 16777216);  // [8192,256]
    u16* s1_b  = (u16*)(ws + 20971520);  // [8192,512]
    u16* x1_b  = (u16*)(ws + 29360128);
    u16* s2_b  = (u16*)(ws + 37748736);
    u16* x2_b  = (u16*)(ws + 46137344);
    u16* W1_b  = (u16*)(ws + 54525952);  // [512,512]
    u16* P1_b  = (u16*)(ws + 55050240);  // [512,1024] = V0+Eg0
    u16* Ed1_b = (u16*)(ws + 56098816);  // [512,512]
    u16* V1_b  = (u16*)(ws + 56623104);
    u16* Eg1_b = (u16*)(ws + 57147392);
    u16* P2_b  = (u16*)(ws + 57671680);  // [512,256] = W2+Ed2
    u16* Bw1_b = (u16*)(ws + 57933824);  // [512,512]
    u16* Bw2_b = (u16*)(ws + 58458112);  // [512,512]
    u16* W0t_b = (u16*)(ws + 58982400);  // [512,1024]
    u16* V1t_b = (u16*)(ws + 60030976);  // [512,512]
    u16* W1t_b = (u16*)(ws + 60555264);  // [512,512]
    u16* V2t_b = (u16*)(ws + 61079552);  // [512,256]
    u16* Eg0_b = (u16*)(ws + 61341696);  // [512,1024]
    u16* Ed2_b = (u16*)(ws + 62390272);  // [512,256]  (end 62652416)

    // stage A: ALL bw2 inputs (transposes + Eg0/Ed2/Ed1/Eg1 bf16)
    PrepAArgs paa;
    paa.tj[0] = { P.W0, W0t_b, 1024,    0 };   // 512 tiles
    paa.tj[1] = { P.V1, V1t_b,  512,  512 };   // 256
    paa.tj[2] = { P.W1, W1t_b,  512,  768 };   // 256
    paa.tj[3] = { P.V2, V2t_b,  256, 1024 };   // 128 -> 1152
    paa.jb[0] = { P.Eg0, nullptr, Eg0_b, 1152 };  // 256 blocks
    paa.jb[1] = { P.Ed2, nullptr, Ed2_b, 1408 };  // 64
    paa.jb[2] = { P.Ed1, nullptr, Ed1_b, 1472 };  // 128
    paa.jb[3] = { P.Eg1, nullptr, Eg1_b, 1600 };  // 128 -> 1728
    k_prep_a<<<dim3(1728), dim3(256), 0, stream>>>(paa);

    // stage B: bw2-fast (128 blocks, dispatched first) + remaining converts
    MergedArgs mg;
    mg.Eg0b = Eg0_b; mg.W0tb = W0t_b; mg.Ed1b = Ed1_b; mg.V1tb = V1t_b;
    mg.Eg1b = Eg1_b; mg.W1tb = W1t_b; mg.Ed2b = Ed2_b; mg.V2tb = V2t_b;
    mg.Bw1b = Bw1_b; mg.Bw2b = Bw2_b;
    mg.jb[0] = { P.x_input,  nullptr, xin_b,     0 };
    mg.jb[1] = { P.y_target, nullptr, y_b,    4096 };
    mg.jb[2] = { P.s1,       nullptr, s1_b,   5120 };
    mg.jb[3] = { P.x1,       nullptr, x1_b,   7168 };
    mg.jb[4] = { P.s2,       nullptr, s2_b,   9216 };
    mg.jb[5] = { P.x2,       nullptr, x2_b,  11264 };
    mg.jb[6] = { P.W1,       nullptr, W1_b,  13312 };
    mg.jb[7] = { P.V0,       P.Eg0,   P1_b,  13440 };
    mg.jb[8] = { P.V1,       nullptr, V1_b,  13696 };
    mg.jb[9] = { P.W2,       P.Ed2,   P2_b,  13824 };   // end 13888 chunks
    // 128 bw blocks + 13888/4 = 3472 convert blocks
    k_merged<<<dim3(3600), dim3(256), 0, stream>>>(mg);

    MArgsF ma;
    ma.j[0].A[0] = s2_b;  ma.j[0].B[0] = W1_b;  ma.j[0].K[0] = 512;
    ma.j[0].A[1] = xin_b; ma.j[0].B[1] = P1_b;  ma.j[0].K[1] = 1024;
    ma.j[0].A[2] = x2_b;  ma.j[0].B[2] = Ed1_b; ma.j[0].K[2] = 512;
    ma.j[0].A[3] = s1_b;  ma.j[0].B[3] = Bw1_b; ma.j[0].K[3] = 512;
    ma.j[0].jin = P.j1; ma.j[0].vin = P.v1; ma.j[0].xin = P.x1; ma.j[0].obase = 0;
    ma.j[1].A[0] = y_b;   ma.j[1].B[0] = P2_b;  ma.j[1].K[0] = 256;
    ma.j[1].A[1] = s1_b;  ma.j[1].B[1] = V1_b;  ma.j[1].K[1] = 512;
    ma.j[1].A[2] = x1_b;  ma.j[1].B[2] = Eg1_b; ma.j[1].K[2] = 512;
    ma.j[1].A[3] = s2_b;  ma.j[1].B[3] = Bw2_b; ma.j[1].K[3] = 512;
    ma.j[1].jin = P.j2; ma.j[1].vin = P.v2; ma.j[1].xin = P.x2; ma.j[1].obase = 2048;
    k_main_fast<<<dim3(1024), dim3(256), 0, stream>>>(ma, out);
  } else {
    k_bw_fb<<<dim3(32), dim3(256), 0, stream>>>(P, out);
    k_main_fb<<<dim3(512), dim3(256), 0, stream>>>(P, out, 0);
    k_main_fb<<<dim3(8), dim3(256), 0, stream>>>(P, out, 1);
  }
}